// Round 12
// baseline (171.255 us; speedup 1.0000x reference)
//
#include <hip/hip_runtime.h>
#include <cstdint>

typedef __bf16 bf16x8 __attribute__((ext_vector_type(8)));
typedef float f32x4 __attribute__((ext_vector_type(4)));
typedef float f32x16 __attribute__((ext_vector_type(16)));

#define NHEADS 12
#define BATCH 4
#define SEQ 2048
#define HID 768
#define DHEAD 64
#define TOTHEADS 48   // BATCH*NHEADS
#define MROWS 8192    // BATCH*SEQ
#define LOG2E 1.4426950408889634f

__device__ __forceinline__ ushort f2bf(float f) {
  union { float f; uint32_t u; } v; v.f = f;
  uint32_t u = v.u;
  uint32_t r = (u + 0x7fffu + ((u >> 16) & 1u)) >> 16;  // RNE
  return (ushort)r;
}

__device__ __forceinline__ float bf2f(ushort u) {
  union { uint32_t u; float f; } v; v.u = (uint32_t)u << 16; return v.f;
}

__device__ __forceinline__ void gload_lds16(const void* g, void* l) {
  __builtin_amdgcn_global_load_lds((const __attribute__((address_space(1))) void*)g,
                                   (__attribute__((address_space(3))) void*)l, 16, 0, 0);
}

// cross-half (lane ^32) add via permlane32_swap (pure VALU)
__device__ __forceinline__ float xor32_add(float x) {
  float t = x;
  asm("v_permlane32_swap_b32 %0, %1" : "+v"(t), "+v"(x));
  return t + x;
}

// ---------------- prep: x->bf16, mask->f32 bias (log2e-scaled), 4x weight transpose ----------------
__global__ void prep_kernel(const float* __restrict__ x, ushort* __restrict__ xb,
                            const float* __restrict__ mask, float* __restrict__ biasArr,
                            const float* __restrict__ W0, const float* __restrict__ W1,
                            const float* __restrict__ W2, const float* __restrict__ W3,
                            ushort* __restrict__ wqkvT, ushort* __restrict__ woT) {
  __shared__ float tile[32][33];
  int bid = blockIdx.x;
  int tid = threadIdx.x;
  if (bid < 6144) {
    int i = bid * 256 + tid;
    const float4 v = *reinterpret_cast<const float4*>(&x[(size_t)i * 4]);
    ushort4 o;
    o.x = f2bf(v.x); o.y = f2bf(v.y); o.z = f2bf(v.z); o.w = f2bf(v.w);
    *reinterpret_cast<ushort4*>(&xb[(size_t)i * 4]) = o;
  } else if (bid < 6152) {
    int i = (bid - 6144) * 256 + tid;   // 0..2047, x4 elems
    const float4 mv = *reinterpret_cast<const float4*>(&mask[(size_t)i * 4]);
    float4 bv;
    bv.x = (1.0f - mv.x) * -10000.0f * LOG2E;
    bv.y = (1.0f - mv.y) * -10000.0f * LOG2E;
    bv.z = (1.0f - mv.z) * -10000.0f * LOG2E;
    bv.w = (1.0f - mv.w) * -10000.0f * LOG2E;
    *reinterpret_cast<float4*>(&biasArr[(size_t)i * 4]) = bv;
  } else {
    int t = bid - 6152;                 // 0 .. 4*576-1
    int z = t / 576, rem = t % 576;
    const float* W = (z == 0) ? W0 : (z == 1) ? W1 : (z == 2) ? W2 : W3;
    ushort* Wt = (z == 3) ? woT : wqkvT + (size_t)z * HID * HID;
    int bx = (rem % 24) * 32;           // n
    int by = (rem / 24) * 32;           // k
    int tx = tid & 31, ty = tid >> 5;   // (32, 8)
#pragma unroll
    for (int i = 0; i < 32; i += 8)
      tile[ty + i][tx] = W[(size_t)(by + ty + i) * HID + bx + tx];
    __syncthreads();
#pragma unroll
    for (int i = 0; i < 32; i += 8)
      Wt[(size_t)(bx + ty + i) * HID + by + tx] = f2bf(tile[tx][ty + i]);
  }
}

// ---------------- shared GEMM mainloop (128x128, double-buffered; no setprio: m190) ----------------
__device__ __forceinline__ void gemm_mainloop(const ushort* __restrict__ A,
                                              const ushort* __restrict__ Bt,
                                              int row0, int col0,
                                              ushort* As, ushort* Bs,
                                              f32x4 (&acc)[4][4], int wv, int lane) {
  const int RW = (wv >> 1) * 64, CW = (wv & 1) * 64;
  const int rr = wv * 16 + (lane >> 2);
  const int cc = (lane & 3) * 8;
  const ushort* A0 = A + (size_t)(row0 + rr) * 768 + cc;
  const ushort* A1 = A + (size_t)(row0 + 64 + rr) * 768 + cc;
  const ushort* B0 = Bt + (size_t)(col0 + rr) * 768 + cc;
  const ushort* B1 = Bt + (size_t)(col0 + 64 + rr) * 768 + cc;
  gload_lds16(A0, As + (wv * 16) * 32);
  gload_lds16(A1, As + (64 + wv * 16) * 32);
  gload_lds16(B0, Bs + (wv * 16) * 32);
  gload_lds16(B1, Bs + (64 + wv * 16) * 32);
  __syncthreads();
  for (int k0 = 0; k0 < 768; k0 += 32) {
    const int buf = (k0 >> 5) & 1;
    if (k0 + 32 < 768) {
      ushort* AsN = As + (buf ^ 1) * (128 * 32);
      ushort* BsN = Bs + (buf ^ 1) * (128 * 32);
      gload_lds16(A0 + k0 + 32, AsN + (wv * 16) * 32);
      gload_lds16(A1 + k0 + 32, AsN + (64 + wv * 16) * 32);
      gload_lds16(B0 + k0 + 32, BsN + (wv * 16) * 32);
      gload_lds16(B1 + k0 + 32, BsN + (64 + wv * 16) * 32);
    }
    const ushort* AsB = As + buf * (128 * 32);
    const ushort* BsB = Bs + buf * (128 * 32);
    bf16x8 a[4], b[4];
#pragma unroll
    for (int m = 0; m < 4; ++m)
      a[m] = *reinterpret_cast<const bf16x8*>(&AsB[(RW + m * 16 + (lane & 15)) * 32 + (lane >> 4) * 8]);
#pragma unroll
    for (int n = 0; n < 4; ++n)
      b[n] = *reinterpret_cast<const bf16x8*>(&BsB[(CW + n * 16 + (lane & 15)) * 32 + (lane >> 4) * 8]);
#pragma unroll
    for (int m = 0; m < 4; ++m)
#pragma unroll
      for (int n = 0; n < 4; ++n)
        acc[m][n] = __builtin_amdgcn_mfma_f32_16x16x32_bf16(a[m], b[n], acc[m][n], 0, 0, 0);
    __syncthreads();
  }
}

// ---------------- fused QKV GEMM ----------------
__global__ __launch_bounds__(256) void gemm_qkv_kernel(const ushort* __restrict__ A,
                                                       const ushort* __restrict__ Bt,
                                                       const float* __restrict__ bq,
                                                       const float* __restrict__ bk,
                                                       const float* __restrict__ bv,
                                                       ushort* __restrict__ Qo,
                                                       ushort* __restrict__ Ko,
                                                       ushort* __restrict__ Vto) {
  __shared__ ushort As[2 * 128 * 32];
  __shared__ ushort Bs[2 * 128 * 32];
  int tid = threadIdx.x, wv = tid >> 6, lane = tid & 63;
  int row0 = blockIdx.x * 128, col0 = blockIdx.y * 128;
  f32x4 acc[4][4] = {};
  gemm_mainloop(A, Bt, row0, col0, As, Bs, acc, wv, lane);

  const int RW = (wv >> 1) * 64, CW = (wv & 1) * 64;
#pragma unroll
  for (int m = 0; m < 4; ++m)
#pragma unroll
    for (int n = 0; n < 4; ++n) {
      int col = col0 + CW + n * 16 + (lane & 15);  // 0..2303
      int t = col / 768, rem = col % 768;
      int hh = rem / 64, d = rem % 64;
      const float* bias = (t == 0) ? bq : ((t == 1) ? bk : bv);
      float bvv = bias[rem];
      int row_base = row0 + RW + m * 16 + (lane >> 4) * 4;
      int bb = row_base >> 11;           // batch
      int s0 = row_base & 2047;          // seq pos of j=0
      int head = bb * NHEADS + hh;
      if (t == 2) {
        ushort4 vv;
        vv.x = f2bf(acc[m][n][0] + bvv);
        vv.y = f2bf(acc[m][n][1] + bvv);
        vv.z = f2bf(acc[m][n][2] + bvv);
        vv.w = f2bf(acc[m][n][3] + bvv);
        *reinterpret_cast<ushort4*>(&Vto[((size_t)head * DHEAD + d) * SEQ + s0]) = vv;
      } else {
        ushort* dst = (t == 0) ? Qo : Ko;
        float scl = (t == 0) ? (0.125f * LOG2E) : 1.0f;  // fold 1/sqrt(64) * log2e into Q
#pragma unroll
        for (int j = 0; j < 4; ++j)
          dst[((size_t)head * SEQ + s0 + j) * DHEAD + d] = f2bf((acc[m][n][j] + bvv) * scl);
      }
    }
}

// ---------------- output projection GEMM: 128x64 tiles (768 blocks; no setprio) ----------------
__global__ __launch_bounds__(256) void gemm_out_kernel(const ushort* __restrict__ A,
                                                       const ushort* __restrict__ Bt,
                                                       const float* __restrict__ bo,
                                                       ushort* __restrict__ tmpb) {
  __shared__ ushort As[2 * 128 * 32];
  __shared__ ushort Bs[2 * 64 * 32];
  int tid = threadIdx.x, wv = tid >> 6, lane = tid & 63;
  int row0 = blockIdx.x * 128, col0 = blockIdx.y * 64;
  const int RW = (wv >> 1) * 64, CW = (wv & 1) * 32;
  const int rr = wv * 16 + (lane >> 2);
  const int cc = (lane & 3) * 8;
  const ushort* A0 = A + (size_t)(row0 + rr) * 768 + cc;
  const ushort* A1 = A + (size_t)(row0 + 64 + rr) * 768 + cc;
  const ushort* B0 = Bt + (size_t)(col0 + rr) * 768 + cc;
  f32x4 acc[4][2] = {};
  gload_lds16(A0, As + (wv * 16) * 32);
  gload_lds16(A1, As + (64 + wv * 16) * 32);
  gload_lds16(B0, Bs + (wv * 16) * 32);
  __syncthreads();
  for (int k0 = 0; k0 < 768; k0 += 32) {
    const int buf = (k0 >> 5) & 1;
    if (k0 + 32 < 768) {
      ushort* AsN = As + (buf ^ 1) * (128 * 32);
      ushort* BsN = Bs + (buf ^ 1) * (64 * 32);
      gload_lds16(A0 + k0 + 32, AsN + (wv * 16) * 32);
      gload_lds16(A1 + k0 + 32, AsN + (64 + wv * 16) * 32);
      gload_lds16(B0 + k0 + 32, BsN + (wv * 16) * 32);
    }
    const ushort* AsB = As + buf * (128 * 32);
    const ushort* BsB = Bs + buf * (64 * 32);
    bf16x8 a[4], b[2];
#pragma unroll
    for (int m = 0; m < 4; ++m)
      a[m] = *reinterpret_cast<const bf16x8*>(&AsB[(RW + m * 16 + (lane & 15)) * 32 + (lane >> 4) * 8]);
#pragma unroll
    for (int n = 0; n < 2; ++n)
      b[n] = *reinterpret_cast<const bf16x8*>(&BsB[(CW + n * 16 + (lane & 15)) * 32 + (lane >> 4) * 8]);
#pragma unroll
    for (int m = 0; m < 4; ++m)
#pragma unroll
      for (int n = 0; n < 2; ++n)
        acc[m][n] = __builtin_amdgcn_mfma_f32_16x16x32_bf16(a[m], b[n], acc[m][n], 0, 0, 0);
    __syncthreads();
  }
#pragma unroll
  for (int m = 0; m < 4; ++m)
#pragma unroll
    for (int n = 0; n < 2; ++n) {
      int col = col0 + CW + n * 16 + (lane & 15);
      float bvv = bo[col];
      int row_base = row0 + RW + m * 16 + (lane >> 4) * 4;
#pragma unroll
      for (int j = 0; j < 4; ++j)
        tmpb[(size_t)(row_base + j) * HID + col] = f2bf(acc[m][n][j] + bvv);
    }
}

// ---------------- flash attention v11: no-max exp2 softmax, deferred l-reduce ----------------
__device__ __forceinline__ void stage_kv(const ushort*& kp0, const ushort*& kp1,
                                         const ushort* vp0, const ushort* vp1, int k0,
                                         ushort* Kd, ushort* Vd, int wb) {
  gload_lds16(kp0, Kd + wb * 64);
  gload_lds16(kp1, Kd + (wb + 8) * 64);
  gload_lds16(vp0 + k0, Vd + wb * 64);
  gload_lds16(vp1 + k0, Vd + (wb + 8) * 64);
  kp0 += 64 * DHEAD; kp1 += 64 * DHEAD;
}

__device__ __forceinline__ void attn_tile(const ushort* __restrict__ KsB,
                                          const ushort* __restrict__ VsB,
                                          const float* __restrict__ biasL, int k0,
                                          const bf16x8 (&bq)[4], bool bz,
                                          f32x16 (&accO)[2], float& lrun,
                                          int lo, int hi) {
  // ---- S = K * Q  (P[key][q]); C init = mask bias[key] (or 0 on fast path) ----
  f32x16 ps[2];
  if (bz) {
#pragma unroll
    for (int kb = 0; kb < 2; ++kb)
#pragma unroll
      for (int r = 0; r < 16; ++r) ps[kb][r] = 0.f;
  } else {
#pragma unroll
    for (int kb = 0; kb < 2; ++kb)
#pragma unroll
      for (int g = 0; g < 4; ++g) {
        const float4 bb = *reinterpret_cast<const float4*>(&biasL[k0 + kb * 32 + g * 8 + hi * 4]);
        ps[kb][g * 4 + 0] = bb.x; ps[kb][g * 4 + 1] = bb.y;
        ps[kb][g * 4 + 2] = bb.z; ps[kb][g * 4 + 3] = bb.w;
      }
  }
  __builtin_amdgcn_s_setprio(1);
#pragma unroll
  for (int kb = 0; kb < 2; ++kb) {
    int key = kb * 32 + lo;
#pragma unroll
    for (int kd = 0; kd < 4; ++kd) {
      bf16x8 ak = *reinterpret_cast<const bf16x8*>(
          &KsB[key * 64 + ((kd * 16 + hi * 8) ^ ((key & 7) << 3))]);
      ps[kb] = __builtin_amdgcn_mfma_f32_32x32x16_bf16(ak, bq[kd], ps[kb], 0, 0, 0);
    }
  }
  __builtin_amdgcn_s_setprio(0);

  // hoist V fragments (ds latency hides under exp2/sum)
  bf16x8 av[2][2][2];
#pragma unroll
  for (int nb = 0; nb < 2; ++nb) {
    int d = nb * 32 + lo;
#pragma unroll
    for (int kb = 0; kb < 2; ++kb)
#pragma unroll
      for (int kk = 0; kk < 2; ++kk)
        av[nb][kb][kk] = *reinterpret_cast<const bf16x8*>(
            &VsB[d * 64 + ((kb * 32 + kk * 16 + hi * 8) ^ ((d & 7) << 3))]);
  }

  // ---- P = exp2(S) directly; l += local sum (cross-half reduce deferred to epilogue) ----
#pragma unroll
  for (int kb = 0; kb < 2; ++kb)
#pragma unroll
    for (int r = 0; r < 16; ++r)
      ps[kb][r] = exp2f(ps[kb][r]);

  float sm[8];
#pragma unroll
  for (int i = 0; i < 8; ++i)
    sm[i] = (ps[0][i] + ps[0][i + 8]) + (ps[1][i] + ps[1][i + 8]);
  lrun += ((sm[0] + sm[1]) + (sm[2] + sm[3])) + ((sm[4] + sm[5]) + (sm[6] + sm[7]));

  // ---- pack P->bf16 + permlane32_swap; O^T += V^T * P ----
  __builtin_amdgcn_s_setprio(1);
#pragma unroll
  for (int kb = 0; kb < 2; ++kb) {
    uint w[8];
#pragma unroll
    for (int i = 0; i < 8; ++i) {
      float a0 = ps[kb][2 * i], a1 = ps[kb][2 * i + 1];
      asm("v_cvt_pk_bf16_f32 %0, %1, %2" : "=v"(w[i]) : "v"(a0), "v"(a1));
    }
    asm("v_permlane32_swap_b32 %0, %1" : "+v"(w[0]), "+v"(w[2]));
    asm("v_permlane32_swap_b32 %0, %1" : "+v"(w[1]), "+v"(w[3]));
    asm("v_permlane32_swap_b32 %0, %1" : "+v"(w[4]), "+v"(w[6]));
    asm("v_permlane32_swap_b32 %0, %1" : "+v"(w[5]), "+v"(w[7]));
    uint4 u0 = make_uint4(w[0], w[1], w[2], w[3]);
    uint4 u1 = make_uint4(w[4], w[5], w[6], w[7]);
    bf16x8 pa0 = __builtin_bit_cast(bf16x8, u0);   // keys kb*32 + 0..15
    bf16x8 pa1 = __builtin_bit_cast(bf16x8, u1);   // keys kb*32 + 16..31
#pragma unroll
    for (int nb = 0; nb < 2; ++nb) {
      accO[nb] = __builtin_amdgcn_mfma_f32_32x32x16_bf16(av[nb][kb][0], pa0, accO[nb], 0, 0, 0);
      accO[nb] = __builtin_amdgcn_mfma_f32_32x32x16_bf16(av[nb][kb][1], pa1, accO[nb], 0, 0, 0);
    }
  }
  __builtin_amdgcn_s_setprio(0);
}

__global__ __launch_bounds__(256, 3) void attn_kernel(const ushort* __restrict__ Q,
                                                      const ushort* __restrict__ Kg,
                                                      const ushort* __restrict__ Vt,
                                                      const float* __restrict__ biasArr,
                                                      ushort* __restrict__ ctx) {
  __shared__ ushort Ks[2][64 * 64];
  __shared__ ushort Vs[2][64 * 64];
  __shared__ float biasL[SEQ];

  int tid = threadIdx.x, wv = tid >> 6, lane = tid & 63;
  int lo = lane & 31, hi = lane >> 5;

  // XCD-grouped swizzle: 768 blocks = 8 XCD * (6 heads * 16 qtiles)
  int bid = blockIdx.x;
  int x = bid & 7, j = bid >> 3;
  int hh = x * 6 + (j >> 4);
  int qt = j & 15;
  int b = hh / NHEADS, h = hh % NHEADS;
  int q0w = qt * 128 + wv * 32;

  const ushort* Qh = Q + (size_t)hh * SEQ * DHEAD;
  const ushort* Kh = Kg + (size_t)hh * SEQ * DHEAD;
  const ushort* Vh = Vt + (size_t)hh * DHEAD * SEQ;
  const float* brow = biasArr + (size_t)b * SEQ;

  // per-thread staging pointers (swizzle col sc is tile-invariant: row&7 == r8)
  int r8 = lane >> 3, sc = ((lane & 7) ^ r8) * 8;
  int wb = wv * 16;
  const ushort* kp0 = Kh + (size_t)(wb + r8) * DHEAD + sc;
  const ushort* kp1 = kp0 + (size_t)8 * DHEAD;
  const ushort* vp0 = Vh + (size_t)(wb + r8) * SEQ + sc;
  const ushort* vp1 = vp0 + (size_t)8 * SEQ;

  // stage bias row into LDS (2048 floats, 8 chunks of 64 lanes x 16B)
#pragma unroll
  for (int c = 0; c < 2; ++c) {
    int chunk = wv * 2 + c;
    gload_lds16(brow + chunk * 256 + lane * 4, biasL + chunk * 256);
  }

  // Q fragments (B operand): col=q=lo, k(d) = kd*16 + hi*8 + j
  bf16x8 bq[4];
#pragma unroll
  for (int kd = 0; kd < 4; ++kd)
    bq[kd] = *reinterpret_cast<const bf16x8*>(&Qh[(size_t)(q0w + lo) * DHEAD + kd * 16 + hi * 8]);

  f32x16 accO[2] = {};           // O^T[d][q]
  float lrun = 0.f;              // per-half partial; cross-half reduced in epilogue

  // prologue: stage tile 0
  stage_kv(kp0, kp1, vp0, vp1, 0, Ks[0], Vs[0], wb);
  __syncthreads();

  // zero-bias fast path check (mask all ones -> bias all zero)
  float bsum = 0.f;
#pragma unroll
  for (int i = 0; i < 2; ++i) {
    const float4 bb = *reinterpret_cast<const float4*>(&biasL[(tid * 2 + i) * 4]);
    bsum += (fabsf(bb.x) + fabsf(bb.y)) + (fabsf(bb.z) + fabsf(bb.w));
  }
  bool bz = __syncthreads_and(bsum == 0.f) != 0;

  for (int k0 = 0; k0 < SEQ; k0 += 128) {
    // body A: stage k0+64 into buf1; compute tile k0 from buf0
    stage_kv(kp0, kp1, vp0, vp1, k0 + 64, Ks[1], Vs[1], wb);
    attn_tile(Ks[0], Vs[0], biasL, k0, bq, bz, accO, lrun, lo, hi);
    __syncthreads();
    // body B: stage k0+128 into buf0; compute tile k0+64 from buf1
    if (k0 + 128 < SEQ)
      stage_kv(kp0, kp1, vp0, vp1, k0 + 128, Ks[0], Vs[0], wb);
    attn_tile(Ks[1], Vs[1], biasL, k0 + 64, bq, bz, accO, lrun, lo, hi);
    if (k0 + 128 < SEQ) __syncthreads();   // last iteration: no LDS reuse follows
  }

  // ---- epilogue: O[q][d] = accO^T / l  (cross-half l-reduce here, once) ----
  lrun = xor32_add(lrun);
  float inv = 1.0f / lrun;
  size_t rowbase = ((size_t)(b * SEQ) + q0w + lo) * HID + h * DHEAD;
#pragma unroll
  for (int nb = 0; nb < 2; ++nb)
#pragma unroll
    for (int g = 0; g < 4; ++g) {
      ushort4 o;
      o.x = f2bf(accO[nb][g * 4 + 0] * inv);
      o.y = f2bf(accO[nb][g * 4 + 1] * inv);
      o.z = f2bf(accO[nb][g * 4 + 2] * inv);
      o.w = f2bf(accO[nb][g * 4 + 3] * inv);
      int d = nb * 32 + g * 8 + hi * 4;
      *reinterpret_cast<ushort4*>(&ctx[rowbase + d]) = o;
    }
}

// ---------------- residual + LayerNorm: one wave per row, bf16 inputs ----------------
__global__ __launch_bounds__(256) void ln_kernel(const ushort* __restrict__ tmpb,
                                                 const ushort* __restrict__ xb,
                                                 const float* __restrict__ g,
                                                 const float* __restrict__ bta,
                                                 float* __restrict__ out) {
  int wv = threadIdx.x >> 6, lane = threadIdx.x & 63;
  int row = blockIdx.x * 4 + wv;
  const ushort* tr = tmpb + (size_t)row * HID;
  const ushort* xr = xb + (size_t)row * HID;
  float v[12];
  float s = 0.f, ss = 0.f;
#pragma unroll
  for (int i = 0; i < 3; ++i) {
    int c = i * 256 + lane * 4;
    ushort4 tv = *reinterpret_cast<const ushort4*>(&tr[c]);
    ushort4 xv = *reinterpret_cast<const ushort4*>(&xr[c]);
    float a0 = bf2f(tv.x) + bf2f(xv.x);
    float a1 = bf2f(tv.y) + bf2f(xv.y);
    float a2 = bf2f(tv.z) + bf2f(xv.z);
    float a3 = bf2f(tv.w) + bf2f(xv.w);
    v[i * 4 + 0] = a0; v[i * 4 + 1] = a1; v[i * 4 + 2] = a2; v[i * 4 + 3] = a3;
    s += (a0 + a1) + (a2 + a3);
    ss += (a0 * a0 + a1 * a1) + (a2 * a2 + a3 * a3);
  }
#pragma unroll
  for (int msk = 1; msk < 64; msk <<= 1) {
    s += __shfl_xor(s, msk);
    ss += __shfl_xor(ss, msk);
  }
  float mu = s * (1.f / HID);
  float var = ss * (1.f / HID) - mu * mu;
  float inv = rsqrtf(var + 1e-5f);
  float* orow = out + (size_t)row * HID;
#pragma unroll
  for (int i = 0; i < 3; ++i) {
    int c = i * 256 + lane * 4;
    const float4 gv = *reinterpret_cast<const float4*>(&g[c]);
    const float4 bv = *reinterpret_cast<const float4*>(&bta[c]);
    float4 ov;
    ov.x = (v[i * 4 + 0] - mu) * inv * gv.x + bv.x;
    ov.y = (v[i * 4 + 1] - mu) * inv * gv.y + bv.y;
    ov.z = (v[i * 4 + 2] - mu) * inv * gv.z + bv.z;
    ov.w = (v[i * 4 + 3] - mu) * inv * gv.w + bv.w;
    *reinterpret_cast<float4*>(&orow[c]) = ov;
  }
}

// ---------------- launch ----------------
extern "C" void kernel_launch(void* const* d_in, const int* in_sizes, int n_in,
                              void* d_out, int out_size, void* d_ws, size_t ws_size,
                              hipStream_t stream) {
  const float* x    = (const float*)d_in[0];
  const float* mask = (const float*)d_in[1];
  const float* Wq   = (const float*)d_in[2];
  const float* bq   = (const float*)d_in[3];
  const float* Wk   = (const float*)d_in[4];
  const float* bk   = (const float*)d_in[5];
  const float* Wv   = (const float*)d_in[6];
  const float* bv   = (const float*)d_in[7];
  const float* Wo   = (const float*)d_in[8];
  const float* bo   = (const float*)d_in[9];
  const float* lng  = (const float*)d_in[10];
  const float* lnb  = (const float*)d_in[11];
  float* out = (float*)d_out;

  char* w = (char*)d_ws;
  size_t o = 0;
  ushort* xb    = (ushort*)(w + o); o += (size_t)MROWS * HID * 2;        // 12.58 MB
  ushort* wqkvT = (ushort*)(w + o); o += (size_t)3 * HID * HID * 2;      // 3.54 MB
  ushort* woT   = (ushort*)(w + o); o += (size_t)HID * HID * 2;          // 1.18 MB
  size_t qb_off = o;
  ushort* Qb    = (ushort*)(w + o); o += (size_t)TOTHEADS * SEQ * DHEAD * 2;
  ushort* Kb    = (ushort*)(w + o); o += (size_t)TOTHEADS * SEQ * DHEAD * 2;
  ushort* Vtb   = (ushort*)(w + o); o += (size_t)TOTHEADS * SEQ * DHEAD * 2;
  ushort* ctx   = (ushort*)(w + o); o += (size_t)MROWS * HID * 2;
  float* biasArr = (float*)(w + o); o += (size_t)BATCH * SEQ * 4;
  ushort* tmpb  = (ushort*)(w + qb_off);  // overlays Q/K (dead by then)

  prep_kernel<<<6152 + 4 * 576, 256, 0, stream>>>(x, xb, mask, biasArr,
                                                  Wq, Wk, Wv, Wo, wqkvT, woT);

  gemm_qkv_kernel<<<dim3(MROWS / 128, 2304 / 128), 256, 0, stream>>>(
      xb, wqkvT, bq, bk, bv, Qb, Kb, Vtb);

  attn_kernel<<<TOTHEADS * 16, 256, 0, stream>>>(Qb, Kb, Vtb, biasArr, ctx);

  gemm_out_kernel<<<dim3(MROWS / 128, HID / 64), 256, 0, stream>>>(ctx, woT, bo, tmpb);

  ln_kernel<<<MROWS / 4, 256, 0, stream>>>(tmpb, xb, lng, lnb, out);
}

// Round 13
// 164.764 us; speedup vs baseline: 1.0394x; 1.0394x over previous
//
#include <hip/hip_runtime.h>
#include <cstdint>

typedef __bf16 bf16x8 __attribute__((ext_vector_type(8)));
typedef float f32x4 __attribute__((ext_vector_type(4)));
typedef float f32x16 __attribute__((ext_vector_type(16)));

#define NHEADS 12
#define BATCH 4
#define SEQ 2048
#define HID 768
#define DHEAD 64
#define TOTHEADS 48   // BATCH*NHEADS
#define MROWS 8192    // BATCH*SEQ
#define LOG2E 1.4426950408889634f

__device__ __forceinline__ ushort f2bf(float f) {
  union { float f; uint32_t u; } v; v.f = f;
  uint32_t u = v.u;
  uint32_t r = (u + 0x7fffu + ((u >> 16) & 1u)) >> 16;  // RNE
  return (ushort)r;
}

__device__ __forceinline__ float bf2f(ushort u) {
  union { uint32_t u; float f; } v; v.u = (uint32_t)u << 16; return v.f;
}

__device__ __forceinline__ void gload_lds16(const void* g, void* l) {
  __builtin_amdgcn_global_load_lds((const __attribute__((address_space(1))) void*)g,
                                   (__attribute__((address_space(3))) void*)l, 16, 0, 0);
}

// cross-half (lane ^32) add via permlane32_swap (pure VALU)
__device__ __forceinline__ float xor32_add(float x) {
  float t = x;
  asm("v_permlane32_swap_b32 %0, %1" : "+v"(t), "+v"(x));
  return t + x;
}

// ---------------- prep: x->bf16, mask->f32 bias (log2e-scaled), 4x weight transpose ----------------
__global__ void prep_kernel(const float* __restrict__ x, ushort* __restrict__ xb,
                            const float* __restrict__ mask, float* __restrict__ biasArr,
                            const float* __restrict__ W0, const float* __restrict__ W1,
                            const float* __restrict__ W2, const float* __restrict__ W3,
                            ushort* __restrict__ wqkvT, ushort* __restrict__ woT) {
  __shared__ float tile[32][33];
  int bid = blockIdx.x;
  int tid = threadIdx.x;
  if (bid < 6144) {
    int i = bid * 256 + tid;
    const float4 v = *reinterpret_cast<const float4*>(&x[(size_t)i * 4]);
    ushort4 o;
    o.x = f2bf(v.x); o.y = f2bf(v.y); o.z = f2bf(v.z); o.w = f2bf(v.w);
    *reinterpret_cast<ushort4*>(&xb[(size_t)i * 4]) = o;
  } else if (bid < 6152) {
    int i = (bid - 6144) * 256 + tid;   // 0..2047, x4 elems
    const float4 mv = *reinterpret_cast<const float4*>(&mask[(size_t)i * 4]);
    float4 bv;
    bv.x = (1.0f - mv.x) * -10000.0f * LOG2E;
    bv.y = (1.0f - mv.y) * -10000.0f * LOG2E;
    bv.z = (1.0f - mv.z) * -10000.0f * LOG2E;
    bv.w = (1.0f - mv.w) * -10000.0f * LOG2E;
    *reinterpret_cast<float4*>(&biasArr[(size_t)i * 4]) = bv;
  } else {
    int t = bid - 6152;                 // 0 .. 4*576-1
    int z = t / 576, rem = t % 576;
    const float* W = (z == 0) ? W0 : (z == 1) ? W1 : (z == 2) ? W2 : W3;
    ushort* Wt = (z == 3) ? woT : wqkvT + (size_t)z * HID * HID;
    int bx = (rem % 24) * 32;           // n
    int by = (rem / 24) * 32;           // k
    int tx = tid & 31, ty = tid >> 5;   // (32, 8)
#pragma unroll
    for (int i = 0; i < 32; i += 8)
      tile[ty + i][tx] = W[(size_t)(by + ty + i) * HID + bx + tx];
    __syncthreads();
#pragma unroll
    for (int i = 0; i < 32; i += 8)
      Wt[(size_t)(bx + ty + i) * HID + by + tx] = f2bf(tile[tx][ty + i]);
  }
}

// ---------------- shared GEMM mainloop (128x128, double-buffered, setprio restored) ----------------
__device__ __forceinline__ void gemm_mainloop(const ushort* __restrict__ A,
                                              const ushort* __restrict__ Bt,
                                              int row0, int col0,
                                              ushort* As, ushort* Bs,
                                              f32x4 (&acc)[4][4], int wv, int lane) {
  const int RW = (wv >> 1) * 64, CW = (wv & 1) * 64;
  const int rr = wv * 16 + (lane >> 2);
  const int cc = (lane & 3) * 8;
  const ushort* A0 = A + (size_t)(row0 + rr) * 768 + cc;
  const ushort* A1 = A + (size_t)(row0 + 64 + rr) * 768 + cc;
  const ushort* B0 = Bt + (size_t)(col0 + rr) * 768 + cc;
  const ushort* B1 = Bt + (size_t)(col0 + 64 + rr) * 768 + cc;
  gload_lds16(A0, As + (wv * 16) * 32);
  gload_lds16(A1, As + (64 + wv * 16) * 32);
  gload_lds16(B0, Bs + (wv * 16) * 32);
  gload_lds16(B1, Bs + (64 + wv * 16) * 32);
  __syncthreads();
  for (int k0 = 0; k0 < 768; k0 += 32) {
    const int buf = (k0 >> 5) & 1;
    if (k0 + 32 < 768) {
      ushort* AsN = As + (buf ^ 1) * (128 * 32);
      ushort* BsN = Bs + (buf ^ 1) * (128 * 32);
      gload_lds16(A0 + k0 + 32, AsN + (wv * 16) * 32);
      gload_lds16(A1 + k0 + 32, AsN + (64 + wv * 16) * 32);
      gload_lds16(B0 + k0 + 32, BsN + (wv * 16) * 32);
      gload_lds16(B1 + k0 + 32, BsN + (64 + wv * 16) * 32);
    }
    const ushort* AsB = As + buf * (128 * 32);
    const ushort* BsB = Bs + buf * (128 * 32);
    bf16x8 a[4], b[4];
#pragma unroll
    for (int m = 0; m < 4; ++m)
      a[m] = *reinterpret_cast<const bf16x8*>(&AsB[(RW + m * 16 + (lane & 15)) * 32 + (lane >> 4) * 8]);
#pragma unroll
    for (int n = 0; n < 4; ++n)
      b[n] = *reinterpret_cast<const bf16x8*>(&BsB[(CW + n * 16 + (lane & 15)) * 32 + (lane >> 4) * 8]);
    __builtin_amdgcn_s_setprio(1);
#pragma unroll
    for (int m = 0; m < 4; ++m)
#pragma unroll
      for (int n = 0; n < 4; ++n)
        acc[m][n] = __builtin_amdgcn_mfma_f32_16x16x32_bf16(a[m], b[n], acc[m][n], 0, 0, 0);
    __builtin_amdgcn_s_setprio(0);
    __syncthreads();
  }
}

// ---------------- fused QKV GEMM ----------------
__global__ __launch_bounds__(256) void gemm_qkv_kernel(const ushort* __restrict__ A,
                                                       const ushort* __restrict__ Bt,
                                                       const float* __restrict__ bq,
                                                       const float* __restrict__ bk,
                                                       const float* __restrict__ bv,
                                                       ushort* __restrict__ Qo,
                                                       ushort* __restrict__ Ko,
                                                       ushort* __restrict__ Vto) {
  __shared__ ushort As[2 * 128 * 32];
  __shared__ ushort Bs[2 * 128 * 32];
  int tid = threadIdx.x, wv = tid >> 6, lane = tid & 63;
  int row0 = blockIdx.x * 128, col0 = blockIdx.y * 128;
  f32x4 acc[4][4] = {};
  gemm_mainloop(A, Bt, row0, col0, As, Bs, acc, wv, lane);

  const int RW = (wv >> 1) * 64, CW = (wv & 1) * 64;
#pragma unroll
  for (int m = 0; m < 4; ++m)
#pragma unroll
    for (int n = 0; n < 4; ++n) {
      int col = col0 + CW + n * 16 + (lane & 15);  // 0..2303
      int t = col / 768, rem = col % 768;
      int hh = rem / 64, d = rem % 64;
      const float* bias = (t == 0) ? bq : ((t == 1) ? bk : bv);
      float bvv = bias[rem];
      int row_base = row0 + RW + m * 16 + (lane >> 4) * 4;
      int bb = row_base >> 11;           // batch
      int s0 = row_base & 2047;          // seq pos of j=0
      int head = bb * NHEADS + hh;
      if (t == 2) {
        ushort4 vv;
        vv.x = f2bf(acc[m][n][0] + bvv);
        vv.y = f2bf(acc[m][n][1] + bvv);
        vv.z = f2bf(acc[m][n][2] + bvv);
        vv.w = f2bf(acc[m][n][3] + bvv);
        *reinterpret_cast<ushort4*>(&Vto[((size_t)head * DHEAD + d) * SEQ + s0]) = vv;
      } else {
        ushort* dst = (t == 0) ? Qo : Ko;
        float scl = (t == 0) ? (0.125f * LOG2E) : 1.0f;  // fold 1/sqrt(64) * log2e into Q
#pragma unroll
        for (int j = 0; j < 4; ++j)
          dst[((size_t)head * SEQ + s0 + j) * DHEAD + d] = f2bf((acc[m][n][j] + bvv) * scl);
      }
    }
}

// ---------------- output projection GEMM: 128x64 tiles (768 blocks, setprio restored) ----------------
__global__ __launch_bounds__(256) void gemm_out_kernel(const ushort* __restrict__ A,
                                                       const ushort* __restrict__ Bt,
                                                       const float* __restrict__ bo,
                                                       ushort* __restrict__ tmpb) {
  __shared__ ushort As[2 * 128 * 32];
  __shared__ ushort Bs[2 * 64 * 32];
  int tid = threadIdx.x, wv = tid >> 6, lane = tid & 63;
  int row0 = blockIdx.x * 128, col0 = blockIdx.y * 64;
  const int RW = (wv >> 1) * 64, CW = (wv & 1) * 32;
  const int rr = wv * 16 + (lane >> 2);
  const int cc = (lane & 3) * 8;
  const ushort* A0 = A + (size_t)(row0 + rr) * 768 + cc;
  const ushort* A1 = A + (size_t)(row0 + 64 + rr) * 768 + cc;
  const ushort* B0 = Bt + (size_t)(col0 + rr) * 768 + cc;
  f32x4 acc[4][2] = {};
  gload_lds16(A0, As + (wv * 16) * 32);
  gload_lds16(A1, As + (64 + wv * 16) * 32);
  gload_lds16(B0, Bs + (wv * 16) * 32);
  __syncthreads();
  for (int k0 = 0; k0 < 768; k0 += 32) {
    const int buf = (k0 >> 5) & 1;
    if (k0 + 32 < 768) {
      ushort* AsN = As + (buf ^ 1) * (128 * 32);
      ushort* BsN = Bs + (buf ^ 1) * (64 * 32);
      gload_lds16(A0 + k0 + 32, AsN + (wv * 16) * 32);
      gload_lds16(A1 + k0 + 32, AsN + (64 + wv * 16) * 32);
      gload_lds16(B0 + k0 + 32, BsN + (wv * 16) * 32);
    }
    const ushort* AsB = As + buf * (128 * 32);
    const ushort* BsB = Bs + buf * (64 * 32);
    bf16x8 a[4], b[2];
#pragma unroll
    for (int m = 0; m < 4; ++m)
      a[m] = *reinterpret_cast<const bf16x8*>(&AsB[(RW + m * 16 + (lane & 15)) * 32 + (lane >> 4) * 8]);
#pragma unroll
    for (int n = 0; n < 2; ++n)
      b[n] = *reinterpret_cast<const bf16x8*>(&BsB[(CW + n * 16 + (lane & 15)) * 32 + (lane >> 4) * 8]);
    __builtin_amdgcn_s_setprio(1);
#pragma unroll
    for (int m = 0; m < 4; ++m)
#pragma unroll
      for (int n = 0; n < 2; ++n)
        acc[m][n] = __builtin_amdgcn_mfma_f32_16x16x32_bf16(a[m], b[n], acc[m][n], 0, 0, 0);
    __builtin_amdgcn_s_setprio(0);
    __syncthreads();
  }
#pragma unroll
  for (int m = 0; m < 4; ++m)
#pragma unroll
    for (int n = 0; n < 2; ++n) {
      int col = col0 + CW + n * 16 + (lane & 15);
      float bvv = bo[col];
      int row_base = row0 + RW + m * 16 + (lane >> 4) * 4;
#pragma unroll
      for (int j = 0; j < 4; ++j)
        tmpb[(size_t)(row_base + j) * HID + col] = f2bf(acc[m][n][j] + bvv);
    }
}

// ---------------- flash attention v11 (unchanged from R12): no-max exp2, deferred l-reduce ----------------
__device__ __forceinline__ void stage_kv(const ushort*& kp0, const ushort*& kp1,
                                         const ushort* vp0, const ushort* vp1, int k0,
                                         ushort* Kd, ushort* Vd, int wb) {
  gload_lds16(kp0, Kd + wb * 64);
  gload_lds16(kp1, Kd + (wb + 8) * 64);
  gload_lds16(vp0 + k0, Vd + wb * 64);
  gload_lds16(vp1 + k0, Vd + (wb + 8) * 64);
  kp0 += 64 * DHEAD; kp1 += 64 * DHEAD;
}

__device__ __forceinline__ void attn_tile(const ushort* __restrict__ KsB,
                                          const ushort* __restrict__ VsB,
                                          const float* __restrict__ biasL, int k0,
                                          const bf16x8 (&bq)[4], bool bz,
                                          f32x16 (&accO)[2], float& lrun,
                                          int lo, int hi) {
  // ---- S = K * Q  (P[key][q]); C init = mask bias[key] (or 0 on fast path) ----
  f32x16 ps[2];
  if (bz) {
#pragma unroll
    for (int kb = 0; kb < 2; ++kb)
#pragma unroll
      for (int r = 0; r < 16; ++r) ps[kb][r] = 0.f;
  } else {
#pragma unroll
    for (int kb = 0; kb < 2; ++kb)
#pragma unroll
      for (int g = 0; g < 4; ++g) {
        const float4 bb = *reinterpret_cast<const float4*>(&biasL[k0 + kb * 32 + g * 8 + hi * 4]);
        ps[kb][g * 4 + 0] = bb.x; ps[kb][g * 4 + 1] = bb.y;
        ps[kb][g * 4 + 2] = bb.z; ps[kb][g * 4 + 3] = bb.w;
      }
  }
  __builtin_amdgcn_s_setprio(1);
#pragma unroll
  for (int kb = 0; kb < 2; ++kb) {
    int key = kb * 32 + lo;
#pragma unroll
    for (int kd = 0; kd < 4; ++kd) {
      bf16x8 ak = *reinterpret_cast<const bf16x8*>(
          &KsB[key * 64 + ((kd * 16 + hi * 8) ^ ((key & 7) << 3))]);
      ps[kb] = __builtin_amdgcn_mfma_f32_32x32x16_bf16(ak, bq[kd], ps[kb], 0, 0, 0);
    }
  }
  __builtin_amdgcn_s_setprio(0);

  // hoist V fragments (ds latency hides under exp2/sum)
  bf16x8 av[2][2][2];
#pragma unroll
  for (int nb = 0; nb < 2; ++nb) {
    int d = nb * 32 + lo;
#pragma unroll
    for (int kb = 0; kb < 2; ++kb)
#pragma unroll
      for (int kk = 0; kk < 2; ++kk)
        av[nb][kb][kk] = *reinterpret_cast<const bf16x8*>(
            &VsB[d * 64 + ((kb * 32 + kk * 16 + hi * 8) ^ ((d & 7) << 3))]);
  }

  // ---- P = exp2(S) directly; l += local sum (cross-half reduce deferred to epilogue) ----
#pragma unroll
  for (int kb = 0; kb < 2; ++kb)
#pragma unroll
    for (int r = 0; r < 16; ++r)
      ps[kb][r] = exp2f(ps[kb][r]);

  float sm[8];
#pragma unroll
  for (int i = 0; i < 8; ++i)
    sm[i] = (ps[0][i] + ps[0][i + 8]) + (ps[1][i] + ps[1][i + 8]);
  lrun += ((sm[0] + sm[1]) + (sm[2] + sm[3])) + ((sm[4] + sm[5]) + (sm[6] + sm[7]));

  // ---- pack P->bf16 + permlane32_swap; O^T += V^T * P ----
  __builtin_amdgcn_s_setprio(1);
#pragma unroll
  for (int kb = 0; kb < 2; ++kb) {
    uint w[8];
#pragma unroll
    for (int i = 0; i < 8; ++i) {
      float a0 = ps[kb][2 * i], a1 = ps[kb][2 * i + 1];
      asm("v_cvt_pk_bf16_f32 %0, %1, %2" : "=v"(w[i]) : "v"(a0), "v"(a1));
    }
    asm("v_permlane32_swap_b32 %0, %1" : "+v"(w[0]), "+v"(w[2]));
    asm("v_permlane32_swap_b32 %0, %1" : "+v"(w[1]), "+v"(w[3]));
    asm("v_permlane32_swap_b32 %0, %1" : "+v"(w[4]), "+v"(w[6]));
    asm("v_permlane32_swap_b32 %0, %1" : "+v"(w[5]), "+v"(w[7]));
    uint4 u0 = make_uint4(w[0], w[1], w[2], w[3]);
    uint4 u1 = make_uint4(w[4], w[5], w[6], w[7]);
    bf16x8 pa0 = __builtin_bit_cast(bf16x8, u0);   // keys kb*32 + 0..15
    bf16x8 pa1 = __builtin_bit_cast(bf16x8, u1);   // keys kb*32 + 16..31
#pragma unroll
    for (int nb = 0; nb < 2; ++nb) {
      accO[nb] = __builtin_amdgcn_mfma_f32_32x32x16_bf16(av[nb][kb][0], pa0, accO[nb], 0, 0, 0);
      accO[nb] = __builtin_amdgcn_mfma_f32_32x32x16_bf16(av[nb][kb][1], pa1, accO[nb], 0, 0, 0);
    }
  }
  __builtin_amdgcn_s_setprio(0);
}

__global__ __launch_bounds__(256, 3) void attn_kernel(const ushort* __restrict__ Q,
                                                      const ushort* __restrict__ Kg,
                                                      const ushort* __restrict__ Vt,
                                                      const float* __restrict__ biasArr,
                                                      ushort* __restrict__ ctx) {
  __shared__ ushort Ks[2][64 * 64];
  __shared__ ushort Vs[2][64 * 64];
  __shared__ float biasL[SEQ];

  int tid = threadIdx.x, wv = tid >> 6, lane = tid & 63;
  int lo = lane & 31, hi = lane >> 5;

  // XCD-grouped swizzle: 768 blocks = 8 XCD * (6 heads * 16 qtiles)
  int bid = blockIdx.x;
  int x = bid & 7, j = bid >> 3;
  int hh = x * 6 + (j >> 4);
  int qt = j & 15;
  int b = hh / NHEADS, h = hh % NHEADS;
  int q0w = qt * 128 + wv * 32;

  const ushort* Qh = Q + (size_t)hh * SEQ * DHEAD;
  const ushort* Kh = Kg + (size_t)hh * SEQ * DHEAD;
  const ushort* Vh = Vt + (size_t)hh * DHEAD * SEQ;
  const float* brow = biasArr + (size_t)b * SEQ;

  // per-thread staging pointers (swizzle col sc is tile-invariant: row&7 == r8)
  int r8 = lane >> 3, sc = ((lane & 7) ^ r8) * 8;
  int wb = wv * 16;
  const ushort* kp0 = Kh + (size_t)(wb + r8) * DHEAD + sc;
  const ushort* kp1 = kp0 + (size_t)8 * DHEAD;
  const ushort* vp0 = Vh + (size_t)(wb + r8) * SEQ + sc;
  const ushort* vp1 = vp0 + (size_t)8 * SEQ;

  // stage bias row into LDS (2048 floats, 8 chunks of 64 lanes x 16B)
#pragma unroll
  for (int c = 0; c < 2; ++c) {
    int chunk = wv * 2 + c;
    gload_lds16(brow + chunk * 256 + lane * 4, biasL + chunk * 256);
  }

  // Q fragments (B operand): col=q=lo, k(d) = kd*16 + hi*8 + j
  bf16x8 bq[4];
#pragma unroll
  for (int kd = 0; kd < 4; ++kd)
    bq[kd] = *reinterpret_cast<const bf16x8*>(&Qh[(size_t)(q0w + lo) * DHEAD + kd * 16 + hi * 8]);

  f32x16 accO[2] = {};           // O^T[d][q]
  float lrun = 0.f;              // per-half partial; cross-half reduced in epilogue

  // prologue: stage tile 0
  stage_kv(kp0, kp1, vp0, vp1, 0, Ks[0], Vs[0], wb);
  __syncthreads();

  // zero-bias fast path check (mask all ones -> bias all zero)
  float bsum = 0.f;
#pragma unroll
  for (int i = 0; i < 2; ++i) {
    const float4 bb = *reinterpret_cast<const float4*>(&biasL[(tid * 2 + i) * 4]);
    bsum += (fabsf(bb.x) + fabsf(bb.y)) + (fabsf(bb.z) + fabsf(bb.w));
  }
  bool bz = __syncthreads_and(bsum == 0.f) != 0;

  for (int k0 = 0; k0 < SEQ; k0 += 128) {
    // body A: stage k0+64 into buf1; compute tile k0 from buf0
    stage_kv(kp0, kp1, vp0, vp1, k0 + 64, Ks[1], Vs[1], wb);
    attn_tile(Ks[0], Vs[0], biasL, k0, bq, bz, accO, lrun, lo, hi);
    __syncthreads();
    // body B: stage k0+128 into buf0; compute tile k0+64 from buf1
    if (k0 + 128 < SEQ)
      stage_kv(kp0, kp1, vp0, vp1, k0 + 128, Ks[0], Vs[0], wb);
    attn_tile(Ks[1], Vs[1], biasL, k0 + 64, bq, bz, accO, lrun, lo, hi);
    if (k0 + 128 < SEQ) __syncthreads();   // last iteration: no LDS reuse follows
  }

  // ---- epilogue: O[q][d] = accO^T / l  (cross-half l-reduce here, once) ----
  lrun = xor32_add(lrun);
  float inv = 1.0f / lrun;
  size_t rowbase = ((size_t)(b * SEQ) + q0w + lo) * HID + h * DHEAD;
#pragma unroll
  for (int nb = 0; nb < 2; ++nb)
#pragma unroll
    for (int g = 0; g < 4; ++g) {
      ushort4 o;
      o.x = f2bf(accO[nb][g * 4 + 0] * inv);
      o.y = f2bf(accO[nb][g * 4 + 1] * inv);
      o.z = f2bf(accO[nb][g * 4 + 2] * inv);
      o.w = f2bf(accO[nb][g * 4 + 3] * inv);
      int d = nb * 32 + g * 8 + hi * 4;
      *reinterpret_cast<ushort4*>(&ctx[rowbase + d]) = o;
    }
}

// ---------------- residual + LayerNorm: one wave per row, bf16 inputs ----------------
__global__ __launch_bounds__(256) void ln_kernel(const ushort* __restrict__ tmpb,
                                                 const ushort* __restrict__ xb,
                                                 const float* __restrict__ g,
                                                 const float* __restrict__ bta,
                                                 float* __restrict__ out) {
  int wv = threadIdx.x >> 6, lane = threadIdx.x & 63;
  int row = blockIdx.x * 4 + wv;
  const ushort* tr = tmpb + (size_t)row * HID;
  const ushort* xr = xb + (size_t)row * HID;
  float v[12];
  float s = 0.f, ss = 0.f;
#pragma unroll
  for (int i = 0; i < 3; ++i) {
    int c = i * 256 + lane * 4;
    ushort4 tv = *reinterpret_cast<const ushort4*>(&tr[c]);
    ushort4 xv = *reinterpret_cast<const ushort4*>(&xr[c]);
    float a0 = bf2f(tv.x) + bf2f(xv.x);
    float a1 = bf2f(tv.y) + bf2f(xv.y);
    float a2 = bf2f(tv.z) + bf2f(xv.z);
    float a3 = bf2f(tv.w) + bf2f(xv.w);
    v[i * 4 + 0] = a0; v[i * 4 + 1] = a1; v[i * 4 + 2] = a2; v[i * 4 + 3] = a3;
    s += (a0 + a1) + (a2 + a3);
    ss += (a0 * a0 + a1 * a1) + (a2 * a2 + a3 * a3);
  }
#pragma unroll
  for (int msk = 1; msk < 64; msk <<= 1) {
    s += __shfl_xor(s, msk);
    ss += __shfl_xor(ss, msk);
  }
  float mu = s * (1.f / HID);
  float var = ss * (1.f / HID) - mu * mu;
  float inv = rsqrtf(var + 1e-5f);
  float* orow = out + (size_t)row * HID;
#pragma unroll
  for (int i = 0; i < 3; ++i) {
    int c = i * 256 + lane * 4;
    const float4 gv = *reinterpret_cast<const float4*>(&g[c]);
    const float4 bv = *reinterpret_cast<const float4*>(&bta[c]);
    float4 ov;
    ov.x = (v[i * 4 + 0] - mu) * inv * gv.x + bv.x;
    ov.y = (v[i * 4 + 1] - mu) * inv * gv.y + bv.y;
    ov.z = (v[i * 4 + 2] - mu) * inv * gv.z + bv.z;
    ov.w = (v[i * 4 + 3] - mu) * inv * gv.w + bv.w;
    *reinterpret_cast<float4*>(&orow[c]) = ov;
  }
}

// ---------------- launch ----------------
extern "C" void kernel_launch(void* const* d_in, const int* in_sizes, int n_in,
                              void* d_out, int out_size, void* d_ws, size_t ws_size,
                              hipStream_t stream) {
  const float* x    = (const float*)d_in[0];
  const float* mask = (const float*)d_in[1];
  const float* Wq   = (const float*)d_in[2];
  const float* bq   = (const float*)d_in[3];
  const float* Wk   = (const float*)d_in[4];
  const float* bk   = (const float*)d_in[5];
  const float* Wv   = (const float*)d_in[6];
  const float* bv   = (const float*)d_in[7];
  const float* Wo   = (const float*)d_in[8];
  const float* bo   = (const float*)d_in[9];
  const float* lng  = (const float*)d_in[10];
  const float* lnb  = (const float*)d_in[11];
  float* out = (float*)d_out;

  char* w = (char*)d_ws;
  size_t o = 0;
  ushort* xb    = (ushort*)(w + o); o += (size_t)MROWS * HID * 2;        // 12.58 MB
  ushort* wqkvT = (ushort*)(w + o); o += (size_t)3 * HID * HID * 2;      // 3.54 MB
  ushort* woT   = (ushort*)(w + o); o += (size_t)HID * HID * 2;          // 1.18 MB
  size_t qb_off = o;
  ushort* Qb    = (ushort*)(w + o); o += (size_t)TOTHEADS * SEQ * DHEAD * 2;
  ushort* Kb    = (ushort*)(w + o); o += (size_t)TOTHEADS * SEQ * DHEAD * 2;
  ushort* Vtb   = (ushort*)(w + o); o += (size_t)TOTHEADS * SEQ * DHEAD * 2;
  ushort* ctx   = (ushort*)(w + o); o += (size_t)MROWS * HID * 2;
  float* biasArr = (float*)(w + o); o += (size_t)BATCH * SEQ * 4;
  ushort* tmpb  = (ushort*)(w + qb_off);  // overlays Q/K (dead by then)

  prep_kernel<<<6152 + 4 * 576, 256, 0, stream>>>(x, xb, mask, biasArr,
                                                  Wq, Wk, Wv, Wo, wqkvT, woT);

  gemm_qkv_kernel<<<dim3(MROWS / 128, 2304 / 128), 256, 0, stream>>>(
      xb, wqkvT, bq, bk, bv, Qb, Kb, Vtb);

  attn_kernel<<<TOTHEADS * 16, 256, 0, stream>>>(Qb, Kb, Vtb, biasArr, ctx);

  gemm_out_kernel<<<dim3(MROWS / 128, HID / 64), 256, 0, stream>>>(ctx, woT, bo, tmpb);

  ln_kernel<<<MROWS / 4, 256, 0, stream>>>(tmpb, xb, lng, lnb, out);
}